// Round 1
// baseline (1673.751 us; speedup 1.0000x reference)
//
#include <hip/hip_runtime.h>
#include <math.h>

#define CH 143
#define XS 145      // xv row stride (odd*..: 145%32=17 -> conflict-free column reads)
#define FS 144      // fmag row stride

// ---------------- Kernel 1: gather + DFT magnitudes + sample staging ----------------
// One block per batch element bi. Loads x[bi] (143x64) coalesced, scatters the 32
// needed position-vectors (rows 24..39 = h in {3,4}; cols (h,3),(h,4)) into LDS,
// computes 72 unique DFT bins per vector (mirror for the rest), writes 32 conv
// samples [2][144] to workspace:  samp[bi*32 + sid][j][c], sid 0..15 raw, 16..31 fft.

__global__ __launch_bounds__(256) void k_prep(const float* __restrict__ x,
                                              float* __restrict__ samp) {
  __shared__ float xv[32 * XS];
  __shared__ float fmag[32 * FS];
  __shared__ float2 tw[CH];

  const int t = threadIdx.x;
  const int bi = blockIdx.x;

  if (t < CH) {
    float ang = 6.2831853071795864769f * (float)t / 143.0f;
    float s, c;
    sincosf(ang, &s, &c);
    tw[t] = make_float2(c, s);
  }

  const float* xb = x + (size_t)bi * (CH * 64);
  for (int i = t; i < CH * 64; i += 256) {
    float v = xb[i];
    int c = i >> 6;
    int pos = i & 63;
    if (pos >= 24 && pos < 40) xv[(pos - 24) * XS + c] = v;       // row vectors v=0..15
    int wc = pos & 7;
    if (wc == 3 || wc == 4)                                        // col vectors v=16..31
      xv[(16 + ((pos >> 3) << 1) + (wc - 3)) * XS + c] = v;
  }
  __syncthreads();

  // DFT chunks 1&2: each lane does 4 vectors x 1 bin; k = (t>>3) + 32*half (0..63)
  {
    const int kq = t >> 3;
    const int v0 = (t & 7) << 2;
    const float* xp = xv + v0 * XS;
    for (int half = 0; half < 2; ++half) {
      int k = kq + (half << 5);
      float ar0 = 0.f, ai0 = 0.f, ar1 = 0.f, ai1 = 0.f;
      float ar2 = 0.f, ai2 = 0.f, ar3 = 0.f, ai3 = 0.f;
      int e = 0;
      for (int n = 0; n < CH; ++n) {
        float2 wv = tw[e];
        float x0 = xp[n];
        float x1 = xp[XS + n];
        float x2 = xp[2 * XS + n];
        float x3 = xp[3 * XS + n];
        ar0 = fmaf(x0, wv.x, ar0); ai0 = fmaf(x0, wv.y, ai0);
        ar1 = fmaf(x1, wv.x, ar1); ai1 = fmaf(x1, wv.y, ai1);
        ar2 = fmaf(x2, wv.x, ar2); ai2 = fmaf(x2, wv.y, ai2);
        ar3 = fmaf(x3, wv.x, ar3); ai3 = fmaf(x3, wv.y, ai3);
        e += k; if (e >= CH) e -= CH;
      }
      float m0 = sqrtf(ar0 * ar0 + ai0 * ai0);
      float m1 = sqrtf(ar1 * ar1 + ai1 * ai1);
      float m2 = sqrtf(ar2 * ar2 + ai2 * ai2);
      float m3 = sqrtf(ar3 * ar3 + ai3 * ai3);
      fmag[(v0 + 0) * FS + k] = m0;
      fmag[(v0 + 1) * FS + k] = m1;
      fmag[(v0 + 2) * FS + k] = m2;
      fmag[(v0 + 3) * FS + k] = m3;
      if (k > 0) {
        fmag[(v0 + 0) * FS + (CH - k)] = m0;
        fmag[(v0 + 1) * FS + (CH - k)] = m1;
        fmag[(v0 + 2) * FS + (CH - k)] = m2;
        fmag[(v0 + 3) * FS + (CH - k)] = m3;
      }
    }
  }
  // DFT chunk 3: k = 64 + (t>>5) (64..71), one vector per lane -> balanced tail
  {
    const int k = 64 + (t >> 5);
    const int v = t & 31;
    const float* xp = xv + v * XS;
    float ar = 0.f, ai = 0.f;
    int e = 0;
    for (int n = 0; n < CH; ++n) {
      float2 wv = tw[e];
      float x0 = xp[n];
      ar = fmaf(x0, wv.x, ar); ai = fmaf(x0, wv.y, ai);
      e += k; if (e >= CH) e -= CH;
    }
    float m = sqrtf(ar * ar + ai * ai);
    fmag[v * FS + k] = m;
    fmag[v * FS + (CH - k)] = m;
  }
  __syncthreads();

  // stage conv samples to workspace: [sid][j][144], c=143 pad -> 0
  float* sb = samp + (size_t)bi * 9216;
  for (int i = t; i < 9216; i += 256) {
    int sid = i / 288;
    int rr = i - sid * 288;
    int j = rr / 144;
    int c = rr - j * 144;
    int u = sid & 15;
    int v = (u < 8) ? (((u >> 2) << 3) + ((u & 3) << 1) + j)   // cr: hi*8 + 2q + j
                    : (16 + ((u & 7) << 1) + j);               // cc: 16 + 2*hi + j
    float val = 0.f;
    if (c < CH) val = (sid < 16) ? xv[v * XS + c] : fmag[v * FS + c];
    sb[i] = val;
  }
}

// ---------------- Kernel 2: conv->LN->ReLU chains ----------------

template<int CIN, int COUT, int LOUT, int ZIS, int ZOS>
__device__ __forceinline__ void conv_stage(int lane, const float* __restrict__ zin,
                                           float* __restrict__ zout,
                                           const float* __restrict__ wgt) {
  constexpr int NOUT = COUT * LOUT;
  for (int id = lane; id < NOUT; id += 64) {
    int co = id / LOUT;
    int p = id - co * LOUT;
    const float* zi = zin + 2 * p;
    const float* wr = wgt + co * (CIN * 3);
    float acc = 0.f;
#pragma unroll
    for (int ci = 0; ci < CIN; ++ci) {
      acc = fmaf(zi[ci * ZIS + 0], wr[ci * 3 + 0], acc);
      acc = fmaf(zi[ci * ZIS + 1], wr[ci * 3 + 1], acc);
      acc = fmaf(zi[ci * ZIS + 2], wr[ci * 3 + 2], acc);
    }
    zout[co * ZOS + p] = acc;
  }
}

template<int NCH, int L, int ZS>
__device__ __forceinline__ void ln_stats(int lane, const float* __restrict__ z,
                                         float* __restrict__ mu, float* __restrict__ inv) {
  if (lane < NCH) {
    const float* row = z + lane * ZS;
    float s = 0.f, s2 = 0.f;
    for (int p = 0; p < L; ++p) {
      float v = row[p];
      s += v;
      s2 = fmaf(v, v, s2);
    }
    float m = s * (1.0f / L);
    float var = s2 * (1.0f / L) - m * m;
    mu[lane] = m;
    inv[lane] = rsqrtf(var + 1e-5f);
  }
}

template<int NCH, int L, int ZS>
__device__ __forceinline__ void ln_apply(int lane, float* __restrict__ z,
                                         const float* __restrict__ mu,
                                         const float* __restrict__ inv,
                                         const float* __restrict__ g,
                                         const float* __restrict__ b) {
  for (int id = lane; id < NCH * L; id += 64) {
    int co = id / L;
    int p = id - co * L;
    float v = (z[co * ZS + p] - mu[co]) * inv[co] * g[p] + b[p];
    z[co * ZS + p] = fmaxf(v, 0.f);
  }
}

// One wave per sample, 4 waves/block, 8 samples per wave (block = 32 samples).
// zA: conv1/conv3 outputs (16x72 max). zB: insamp / conv2 / conv4 outputs (28x36 max).
template<int C1, int C2, bool BIG>
__device__ void run_chain(const float* __restrict__ samp, float* __restrict__ out,
                          const float* __restrict__ warena,
                          float* zA, float* zB, float* mu, float* inv,
                          int ow1, int ow2, int ow3, int ow4,
                          int sBase, int w, int lane) {
  const float* g1 = warena + 6144; const float* b1 = warena + 6215;
  const float* g2 = warena + 6286; const float* b2 = warena + 6321;
  const float* g3 = warena + 6356; const float* b3 = warena + 6373;
  const float* g4 = warena + 6390; const float* b4 = warena + 6398;
  for (int r = 0; r < 8; ++r) {
    int sIdx = sBase + w * 8 + r;
    int bi = sIdx >> 4;
    int u = sIdx & 15;
    int sid = BIG ? u : (16 + u);
    const float* src = samp + ((size_t)bi * 32 + sid) * 288;
    float* insamp = zB;                      // reuse zB region for the input sample
    for (int i = lane; i < 288; i += 64) insamp[i] = src[i];
    __syncthreads();
    conv_stage<2, C1, 71, 144, 72>(lane, insamp, zA, warena + ow1);
    __syncthreads();
    ln_stats<C1, 71, 72>(lane, zA, mu, inv);
    __syncthreads();
    ln_apply<C1, 71, 72>(lane, zA, mu, inv, g1, b1);
    __syncthreads();
    conv_stage<C1, C2, 35, 72, 36>(lane, zA, zB, warena + ow2);
    __syncthreads();
    ln_stats<C2, 35, 36>(lane, zB, mu, inv);
    __syncthreads();
    ln_apply<C2, 35, 36>(lane, zB, mu, inv, g2, b2);
    __syncthreads();
    conv_stage<C2, C2, 17, 36, 18>(lane, zB, zA, warena + ow3);
    __syncthreads();
    ln_stats<C2, 17, 18>(lane, zA, mu, inv);
    __syncthreads();
    ln_apply<C2, 17, 18>(lane, zA, mu, inv, g3, b3);
    __syncthreads();
    conv_stage<C2, C2, 8, 18, 8>(lane, zA, zB, warena + ow4);
    __syncthreads();
    ln_stats<C2, 8, 8>(lane, zB, mu, inv);
    __syncthreads();
    ln_apply<C2, 8, 8>(lane, zB, mu, inv, g4, b4);
    __syncthreads();
    // store: out[bi][cb+co][s][l], flat = bi*4096 + (cb+co)*64 + s*8 + l
    int cb = BIG ? ((u < 8) ? 0 : 28) : ((u < 8) ? 56 : 60);
    int s = u & 7;
    size_t obase = (size_t)bi * 4096 + (size_t)cb * 64 + (size_t)s * 8;
    for (int id = lane; id < C2 * 8; id += 64) {
      int co = id >> 3, ll = id & 7;
      out[obase + (size_t)co * 64 + ll] = zB[co * 8 + ll];
    }
    __syncthreads();
  }
}

__global__ __launch_bounds__(256) void k_conv(
    const float* __restrict__ samp,
    const float* __restrict__ w1, const float* __restrict__ w2,
    const float* __restrict__ w3, const float* __restrict__ w4,
    const float* __restrict__ f1, const float* __restrict__ f2,
    const float* __restrict__ f3, const float* __restrict__ f4,
    const float* __restrict__ l1g, const float* __restrict__ l1b,
    const float* __restrict__ l2g, const float* __restrict__ l2b,
    const float* __restrict__ l3g, const float* __restrict__ l3b,
    const float* __restrict__ l4g, const float* __restrict__ l4b,
    float* __restrict__ out) {
  __shared__ float warena[6406];
  __shared__ float slots[4][2216];

  const int t = threadIdx.x;
  const int w = t >> 6;
  const int lane = t & 63;
  const bool big = blockIdx.x < 2048;

  if (big) {
    for (int i = t; i < 96; i += 256)   warena[i]        = w1[i];
    for (int i = t; i < 1344; i += 256) warena[96 + i]   = w2[i];
    for (int i = t; i < 2352; i += 256) warena[1440 + i] = w3[i];
    for (int i = t; i < 2352; i += 256) warena[3792 + i] = w4[i];
  } else {
    for (int i = t; i < 24; i += 256)   warena[i]        = f1[i];
    for (int i = t; i < 48; i += 256)   warena[24 + i]   = f2[i];
    for (int i = t; i < 48; i += 256)   warena[72 + i]   = f3[i];
    for (int i = t; i < 48; i += 256)   warena[120 + i]  = f4[i];
  }
  for (int i = t; i < 71; i += 256) { warena[6144 + i] = l1g[i]; warena[6215 + i] = l1b[i]; }
  for (int i = t; i < 35; i += 256) { warena[6286 + i] = l2g[i]; warena[6321 + i] = l2b[i]; }
  for (int i = t; i < 17; i += 256) { warena[6356 + i] = l3g[i]; warena[6373 + i] = l3b[i]; }
  for (int i = t; i < 8;  i += 256) { warena[6390 + i] = l4g[i]; warena[6398 + i] = l4b[i]; }
  __syncthreads();

  float* zA = slots[w];
  float* zB = zA + 1152;
  float* mu = zA + 2160;
  float* inv = zA + 2188;

  if (big)
    run_chain<16, 28, true >(samp, out, warena, zA, zB, mu, inv, 0, 96, 1440, 3792,
                             (int)blockIdx.x * 32, w, lane);
  else
    run_chain<4, 4, false>(samp, out, warena, zA, zB, mu, inv, 0, 24, 72, 120,
                             ((int)blockIdx.x - 2048) * 32, w, lane);
}

extern "C" void kernel_launch(void* const* d_in, const int* in_sizes, int n_in,
                              void* d_out, int out_size, void* d_ws, size_t ws_size,
                              hipStream_t stream) {
  const float* x   = (const float*)d_in[0];
  const float* w1  = (const float*)d_in[1];
  const float* w2  = (const float*)d_in[2];
  const float* w3  = (const float*)d_in[3];
  const float* w4  = (const float*)d_in[4];
  const float* f1  = (const float*)d_in[5];
  const float* f2  = (const float*)d_in[6];
  const float* f3  = (const float*)d_in[7];
  const float* f4  = (const float*)d_in[8];
  const float* l1g = (const float*)d_in[9];
  const float* l1b = (const float*)d_in[10];
  const float* l2g = (const float*)d_in[11];
  const float* l2b = (const float*)d_in[12];
  const float* l3g = (const float*)d_in[13];
  const float* l3b = (const float*)d_in[14];
  const float* l4g = (const float*)d_in[15];
  const float* l4b = (const float*)d_in[16];
  float* out = (float*)d_out;
  float* samp = (float*)d_ws;   // 4096 * 32 samples * 2 * 144 floats = 151 MB

  k_prep<<<4096, 256, 0, stream>>>(x, samp);
  k_conv<<<4096, 256, 0, stream>>>(samp, w1, w2, w3, w4, f1, f2, f3, f4,
                                   l1g, l1b, l2g, l2b, l3g, l3b, l4g, l4b, out);
}

// Round 2
// 1607.182 us; speedup vs baseline: 1.0414x; 1.0414x over previous
//
#include <hip/hip_runtime.h>
#include <math.h>

#define CH 143
#define XS 145      // xv row stride
#define FS 144      // fmag row stride

__device__ __forceinline__ void wsync() {
  asm volatile("s_waitcnt lgkmcnt(0)" ::: "memory");
  __builtin_amdgcn_wave_barrier();
}

// ---------------- Kernel 1: gather + DFT magnitudes + sample staging (unchanged) ----

__global__ __launch_bounds__(256) void k_prep(const float* __restrict__ x,
                                              float* __restrict__ samp) {
  __shared__ float xv[32 * XS];
  __shared__ float fmag[32 * FS];
  __shared__ float2 tw[CH];

  const int t = threadIdx.x;
  const int bi = blockIdx.x;

  if (t < CH) {
    float ang = 6.2831853071795864769f * (float)t / 143.0f;
    float s, c;
    sincosf(ang, &s, &c);
    tw[t] = make_float2(c, s);
  }

  const float* xb = x + (size_t)bi * (CH * 64);
  for (int i = t; i < CH * 64; i += 256) {
    float v = xb[i];
    int c = i >> 6;
    int pos = i & 63;
    if (pos >= 24 && pos < 40) xv[(pos - 24) * XS + c] = v;
    int wc = pos & 7;
    if (wc == 3 || wc == 4)
      xv[(16 + ((pos >> 3) << 1) + (wc - 3)) * XS + c] = v;
  }
  __syncthreads();

  {
    const int kq = t >> 3;
    const int v0 = (t & 7) << 2;
    const float* xp = xv + v0 * XS;
    for (int half = 0; half < 2; ++half) {
      int k = kq + (half << 5);
      float ar0 = 0.f, ai0 = 0.f, ar1 = 0.f, ai1 = 0.f;
      float ar2 = 0.f, ai2 = 0.f, ar3 = 0.f, ai3 = 0.f;
      int e = 0;
      for (int n = 0; n < CH; ++n) {
        float2 wv = tw[e];
        float x0 = xp[n];
        float x1 = xp[XS + n];
        float x2 = xp[2 * XS + n];
        float x3 = xp[3 * XS + n];
        ar0 = fmaf(x0, wv.x, ar0); ai0 = fmaf(x0, wv.y, ai0);
        ar1 = fmaf(x1, wv.x, ar1); ai1 = fmaf(x1, wv.y, ai1);
        ar2 = fmaf(x2, wv.x, ar2); ai2 = fmaf(x2, wv.y, ai2);
        ar3 = fmaf(x3, wv.x, ar3); ai3 = fmaf(x3, wv.y, ai3);
        e += k; if (e >= CH) e -= CH;
      }
      float m0 = sqrtf(ar0 * ar0 + ai0 * ai0);
      float m1 = sqrtf(ar1 * ar1 + ai1 * ai1);
      float m2 = sqrtf(ar2 * ar2 + ai2 * ai2);
      float m3 = sqrtf(ar3 * ar3 + ai3 * ai3);
      fmag[(v0 + 0) * FS + k] = m0;
      fmag[(v0 + 1) * FS + k] = m1;
      fmag[(v0 + 2) * FS + k] = m2;
      fmag[(v0 + 3) * FS + k] = m3;
      if (k > 0) {
        fmag[(v0 + 0) * FS + (CH - k)] = m0;
        fmag[(v0 + 1) * FS + (CH - k)] = m1;
        fmag[(v0 + 2) * FS + (CH - k)] = m2;
        fmag[(v0 + 3) * FS + (CH - k)] = m3;
      }
    }
  }
  {
    const int k = 64 + (t >> 5);
    const int v = t & 31;
    const float* xp = xv + v * XS;
    float ar = 0.f, ai = 0.f;
    int e = 0;
    for (int n = 0; n < CH; ++n) {
      float2 wv = tw[e];
      float x0 = xp[n];
      ar = fmaf(x0, wv.x, ar); ai = fmaf(x0, wv.y, ai);
      e += k; if (e >= CH) e -= CH;
    }
    float m = sqrtf(ar * ar + ai * ai);
    fmag[v * FS + k] = m;
    fmag[v * FS + (CH - k)] = m;
  }
  __syncthreads();

  float* sb = samp + (size_t)bi * 9216;
  for (int i = t; i < 9216; i += 256) {
    int sid = i / 288;
    int rr = i - sid * 288;
    int j = rr / 144;
    int c = rr - j * 144;
    int u = sid & 15;
    int v = (u < 8) ? (((u >> 2) << 3) + ((u & 3) << 1) + j)
                    : (16 + ((u & 7) << 1) + j);
    float val = 0.f;
    if (c < CH) val = (sid < 16) ? xv[v * XS + c] : fmag[v * FS + c];
    sb[i] = val;
  }
}

// ---------------- Kernel 2: conv->LN->ReLU chains (rewritten) ----------------
// LDS layout per block:  4 wave slots (SLOT floats) + arena.
// Big path slot: insamp[2][144] @0, z1[71][16] @288 (transposed [pos][ci]),
//                z2/z4 [35][28] @1424. z3 overlays z1.
#define SLOT 2432
#define Z1O 288
#define Z2O 1424
#define ARENA (4 * SLOT)
#define AF1 0
#define AF2 24
#define AF3 72
#define AF4 120
#define AG1 168
#define AB1 239
#define AG2 310
#define AB2 345
#define AG3 380
#define AB3 397
#define AG4 414
#define AB4 422

// LN for stride-28 [pos][co] buffers; lanes = (cc<28, ph half). Stats in regs.
template<int L, int HL>
__device__ __forceinline__ void ln_half(float* __restrict__ zs,
                                        const float* __restrict__ g,
                                        const float* __restrict__ b,
                                        int cc, int ph, bool act) {
  float s = 0.f, s2 = 0.f;
#pragma unroll
  for (int pp = 0; pp < HL; ++pp) {
    int p = ph * HL + pp;
    if (p < L) { float v = zs[p * 28 + cc]; s += v; s2 = fmaf(v, v, s2); }
  }
  s += __shfl_xor(s, 32); s2 += __shfl_xor(s2, 32);
  float mu = s * (1.0f / L);
  float inv = rsqrtf(s2 * (1.0f / L) - mu * mu + 1e-5f);
#pragma unroll
  for (int pp = 0; pp < HL; ++pp) {
    int p = ph * HL + pp;
    if (p < L && act) {
      int idx = p * 28 + cc;
      float v = (zs[idx] - mu) * inv * g[p] + b[p];
      zs[idx] = fmaxf(v, 0.f);
    }
  }
}

// CIN=28 conv stage, input [pos][28], output [p][28]; weights in VGPRs.
template<int LOUT, int HL>
__device__ __forceinline__ void conv28(const float* __restrict__ zin,
                                       float* __restrict__ zout,
                                       const float* __restrict__ wr,
                                       int cc, int ph, bool act) {
  for (int pp = 0; pp < HL; ++pp) {
    int p = ph * HL + pp;
    if (p < LOUT) {
      const float* r0 = zin + 2 * p * 28;
      float a0 = 0.f, a1 = 0.f, a2 = 0.f, a3 = 0.f;
#pragma unroll
      for (int cq = 0; cq < 7; ++cq) {
        float4 ra = *(const float4*)(r0 + 4 * cq);
        float4 rb = *(const float4*)(r0 + 28 + 4 * cq);
        float4 rc = *(const float4*)(r0 + 56 + 4 * cq);
        const int k = cq * 12;
        a0 = fmaf(ra.x, wr[k + 0], a0); a0 = fmaf(rb.x, wr[k + 1], a0); a0 = fmaf(rc.x, wr[k + 2], a0);
        a1 = fmaf(ra.y, wr[k + 3], a1); a1 = fmaf(rb.y, wr[k + 4], a1); a1 = fmaf(rc.y, wr[k + 5], a1);
        a2 = fmaf(ra.z, wr[k + 6], a2); a2 = fmaf(rb.z, wr[k + 7], a2); a2 = fmaf(rc.z, wr[k + 8], a2);
        a3 = fmaf(ra.w, wr[k + 9], a3); a3 = fmaf(rb.w, wr[k + 10], a3); a3 = fmaf(rc.w, wr[k + 11], a3);
      }
      if (act) zout[p * 28 + cc] = (a0 + a1) + (a2 + a3);
    }
  }
}

// ---- small chain (old flattened structure, wave-local sync) ----
template<int CIN, int COUT, int LOUT, int ZIS, int ZOS>
__device__ __forceinline__ void conv_stage_s(int lane, const float* __restrict__ zin,
                                             float* __restrict__ zout,
                                             const float* __restrict__ wgt) {
  constexpr int NOUT = COUT * LOUT;
  for (int id = lane; id < NOUT; id += 64) {
    int co = id / LOUT;
    int p = id - co * LOUT;
    const float* zi = zin + 2 * p;
    const float* wrp = wgt + co * (CIN * 3);
    float acc = 0.f;
#pragma unroll
    for (int ci = 0; ci < CIN; ++ci) {
      acc = fmaf(zi[ci * ZIS + 0], wrp[ci * 3 + 0], acc);
      acc = fmaf(zi[ci * ZIS + 1], wrp[ci * 3 + 1], acc);
      acc = fmaf(zi[ci * ZIS + 2], wrp[ci * 3 + 2], acc);
    }
    zout[co * ZOS + p] = acc;
  }
}

template<int NCH, int L, int ZS>
__device__ __forceinline__ void ln_stats_s(int lane, const float* __restrict__ z,
                                           float* __restrict__ mu, float* __restrict__ inv) {
  if (lane < NCH) {
    const float* row = z + lane * ZS;
    float s = 0.f, s2 = 0.f;
    for (int p = 0; p < L; ++p) { float v = row[p]; s += v; s2 = fmaf(v, v, s2); }
    float m = s * (1.0f / L);
    float var = s2 * (1.0f / L) - m * m;
    mu[lane] = m;
    inv[lane] = rsqrtf(var + 1e-5f);
  }
}

template<int NCH, int L, int ZS>
__device__ __forceinline__ void ln_apply_s(int lane, float* __restrict__ z,
                                           const float* __restrict__ mu,
                                           const float* __restrict__ inv,
                                           const float* __restrict__ g,
                                           const float* __restrict__ b) {
  for (int id = lane; id < NCH * L; id += 64) {
    int co = id / L;
    int p = id - co * L;
    float v = (z[co * ZS + p] - mu[co]) * inv[co] * g[p] + b[p];
    z[co * ZS + p] = fmaxf(v, 0.f);
  }
}

__global__ __launch_bounds__(256) void k_conv(
    const float* __restrict__ samp,
    const float* __restrict__ w1, const float* __restrict__ w2,
    const float* __restrict__ w3, const float* __restrict__ w4,
    const float* __restrict__ f1, const float* __restrict__ f2,
    const float* __restrict__ f3, const float* __restrict__ f4,
    const float* __restrict__ l1g, const float* __restrict__ l1b,
    const float* __restrict__ l2g, const float* __restrict__ l2b,
    const float* __restrict__ l3g, const float* __restrict__ l3b,
    const float* __restrict__ l4g, const float* __restrict__ l4b,
    float* __restrict__ out) {
  __shared__ float lds[4 * SLOT + 448];

  const int t = threadIdx.x;
  const int w = t >> 6;
  const int lane = t & 63;
  const bool big = blockIdx.x < 2048;
  float* A = lds + ARENA;

  // arena: LN params (all blocks) + f-weights (small blocks)
  if (!big) {
    for (int i = t; i < 24; i += 256) A[AF1 + i] = f1[i];
    for (int i = t; i < 48; i += 256) {
      A[AF2 + i] = f2[i]; A[AF3 + i] = f3[i]; A[AF4 + i] = f4[i];
    }
  }
  for (int i = t; i < 71; i += 256) { A[AG1 + i] = l1g[i]; A[AB1 + i] = l1b[i]; }
  for (int i = t; i < 35; i += 256) { A[AG2 + i] = l2g[i]; A[AB2 + i] = l2b[i]; }
  for (int i = t; i < 17; i += 256) { A[AG3 + i] = l3g[i]; A[AB3 + i] = l3b[i]; }
  if (t < 8) { A[AG4 + t] = l4g[t]; A[AB4 + t] = l4b[t]; }
  __syncthreads();

  float* slot = lds + w * SLOT;
  const float* g1 = A + AG1; const float* b1 = A + AB1;
  const float* g2 = A + AG2; const float* b2 = A + AB2;
  const float* g3 = A + AG3; const float* b3 = A + AB3;
  const float* g4 = A + AG4; const float* b4 = A + AB4;

  if (big) {
    float* insamp = slot;
    float* z1 = slot + Z1O;   // [pos][16], also z3 [p][28]
    float* z2 = slot + Z2O;   // [p][28], also z4

    const int cc = lane & 31;
    const int ph = lane >> 5;
    const int co1 = lane & 15;
    const int q1 = lane >> 4;
    const int cw = (cc < 28) ? cc : 27;
    const bool act = cc < 28;

    float w1r[6];
    {
      const float* wp = w1 + co1 * 6;
#pragma unroll
      for (int k = 0; k < 6; ++k) w1r[k] = wp[k];
    }

    const int sBase = (int)blockIdx.x * 32 + w * 8;
    for (int rr = 0; rr < 8; ++rr) {
      const int sIdx = sBase + rr;
      const int bi = sIdx >> 4;
      const int u = sIdx & 15;
      const float* src = samp + (size_t)(bi * 32 + u) * 288;
      // stage input sample (288 floats = 72 float4)
      ((float4*)insamp)[lane] = ((const float4*)src)[lane & 63];
      if (lane < 8) ((float4*)insamp)[64 + lane] = ((const float4*)src)[64 + lane];
      // weights for conv2 (global, L2-hot)
      float w2r[48];
      {
        const float* wp = w2 + cw * 48;
#pragma unroll
        for (int k = 0; k < 12; ++k) ((float4*)w2r)[k] = ((const float4*)wp)[k];
      }
      wsync();
      // conv1: lanes (co1, q1): p = q1 + 4*i ; out z1[p][co1]
#pragma unroll
      for (int i = 0; i < 18; ++i) {
        int p = q1 + 4 * i;
        if (p < 71) {
          const float* ip = insamp + 2 * p;
          float2 xa = *(const float2*)(ip);
          float x2 = ip[2];
          float2 ya = *(const float2*)(ip + 144);
          float y2 = ip[146];
          float acc = xa.x * w1r[0];
          acc = fmaf(xa.y, w1r[1], acc);
          acc = fmaf(x2, w1r[2], acc);
          acc = fmaf(ya.x, w1r[3], acc);
          acc = fmaf(ya.y, w1r[4], acc);
          acc = fmaf(y2, w1r[5], acc);
          z1[p * 16 + co1] = acc;
        }
      }
      wsync();
      // LN1: lanes (co1, q1 quarter), stats via shuffles
      {
        float s = 0.f, s2 = 0.f;
#pragma unroll
        for (int pp = 0; pp < 18; ++pp) {
          int p = q1 * 18 + pp;
          if (p < 71) { float v = z1[p * 16 + co1]; s += v; s2 = fmaf(v, v, s2); }
        }
        s += __shfl_xor(s, 16); s2 += __shfl_xor(s2, 16);
        s += __shfl_xor(s, 32); s2 += __shfl_xor(s2, 32);
        float mu = s * (1.0f / 71.0f);
        float inv = rsqrtf(s2 * (1.0f / 71.0f) - mu * mu + 1e-5f);
#pragma unroll
        for (int pp = 0; pp < 18; ++pp) {
          int p = q1 * 18 + pp;
          if (p < 71) {
            int idx = p * 16 + co1;
            float v = (z1[idx] - mu) * inv * g1[p] + b1[p];
            z1[idx] = fmaxf(v, 0.f);
          }
        }
      }
      wsync();
      // conv2: lanes (cc, ph); input z1 [pos][16], output z2 [p][28]
      for (int pp = 0; pp < 18; ++pp) {
        int p = ph * 18 + pp;
        if (p < 35) {
          const float* r0 = z1 + 32 * p;
          float a0 = 0.f, a1 = 0.f, a2 = 0.f, a3 = 0.f;
#pragma unroll
          for (int cq = 0; cq < 4; ++cq) {
            float4 ra = *(const float4*)(r0 + 4 * cq);
            float4 rb = *(const float4*)(r0 + 16 + 4 * cq);
            float4 rc = *(const float4*)(r0 + 32 + 4 * cq);
            const int k = cq * 12;
            a0 = fmaf(ra.x, w2r[k + 0], a0); a0 = fmaf(rb.x, w2r[k + 1], a0); a0 = fmaf(rc.x, w2r[k + 2], a0);
            a1 = fmaf(ra.y, w2r[k + 3], a1); a1 = fmaf(rb.y, w2r[k + 4], a1); a1 = fmaf(rc.y, w2r[k + 5], a1);
            a2 = fmaf(ra.z, w2r[k + 6], a2); a2 = fmaf(rb.z, w2r[k + 7], a2); a2 = fmaf(rc.z, w2r[k + 8], a2);
            a3 = fmaf(ra.w, w2r[k + 9], a3); a3 = fmaf(rb.w, w2r[k + 10], a3); a3 = fmaf(rc.w, w2r[k + 11], a3);
          }
          if (act) z2[p * 28 + cc] = (a0 + a1) + (a2 + a3);
        }
      }
      wsync();
      ln_half<35, 18>(z2, g2, b2, cc, ph, act);
      wsync();
      // conv3
      float w3r[84];
      {
        const float* wp = w3 + cw * 84;
#pragma unroll
        for (int k = 0; k < 21; ++k) ((float4*)w3r)[k] = ((const float4*)wp)[k];
      }
      conv28<17, 9>(z2, z1, w3r, cc, ph, act);
      wsync();
      ln_half<17, 9>(z1, g3, b3, cc, ph, act);
      wsync();
      // conv4
      float w4r[84];
      {
        const float* wp = w4 + cw * 84;
#pragma unroll
        for (int k = 0; k < 21; ++k) ((float4*)w4r)[k] = ((const float4*)wp)[k];
      }
      conv28<8, 4>(z1, z2, w4r, cc, ph, act);
      wsync();
      // LN4 + ReLU + store
      {
        float s = 0.f, s2 = 0.f;
#pragma unroll
        for (int pp = 0; pp < 4; ++pp) {
          int p = ph * 4 + pp;
          float v = z2[p * 28 + cc]; s += v; s2 = fmaf(v, v, s2);
        }
        s += __shfl_xor(s, 32); s2 += __shfl_xor(s2, 32);
        float mu = s * 0.125f;
        float inv = rsqrtf(s2 * 0.125f - mu * mu + 1e-5f);
        int cb = (u < 8) ? 0 : 28;
        size_t obase = (size_t)bi * 4096 + (size_t)cb * 64 + (size_t)(u & 7) * 8;
        if (act) {
#pragma unroll
          for (int pp = 0; pp < 4; ++pp) {
            int p = ph * 4 + pp;
            float v = (z2[p * 28 + cc] - mu) * inv * g4[p] + b4[p];
            out[obase + (size_t)cc * 64 + p] = fmaxf(v, 0.f);
          }
        }
      }
      wsync();
    }
  } else {
    // ---- small chain: old flattened path, wave-local sync ----
    float* zA = slot;
    float* zB = slot + 1152;
    float* mu = slot + 2160;
    float* inv = slot + 2188;
    const float* fw1 = A + AF1; const float* fw2 = A + AF2;
    const float* fw3 = A + AF3; const float* fw4 = A + AF4;
    const int sBase = ((int)blockIdx.x - 2048) * 32;
    for (int r = 0; r < 8; ++r) {
      int sIdx = sBase + w * 8 + r;
      int bi = sIdx >> 4;
      int u = sIdx & 15;
      const float* src = samp + ((size_t)bi * 32 + 16 + u) * 288;
      float* insamp = zB;
      for (int i = lane; i < 288; i += 64) insamp[i] = src[i];
      wsync();
      conv_stage_s<2, 4, 71, 144, 72>(lane, insamp, zA, fw1);
      wsync();
      ln_stats_s<4, 71, 72>(lane, zA, mu, inv);
      wsync();
      ln_apply_s<4, 71, 72>(lane, zA, mu, inv, g1, b1);
      wsync();
      conv_stage_s<4, 4, 35, 72, 36>(lane, zA, zB, fw2);
      wsync();
      ln_stats_s<4, 35, 36>(lane, zB, mu, inv);
      wsync();
      ln_apply_s<4, 35, 36>(lane, zB, mu, inv, g2, b2);
      wsync();
      conv_stage_s<4, 4, 17, 36, 18>(lane, zB, zA, fw3);
      wsync();
      ln_stats_s<4, 17, 18>(lane, zA, mu, inv);
      wsync();
      ln_apply_s<4, 17, 18>(lane, zA, mu, inv, g3, b3);
      wsync();
      conv_stage_s<4, 4, 8, 18, 8>(lane, zA, zB, fw4);
      wsync();
      ln_stats_s<4, 8, 8>(lane, zB, mu, inv);
      wsync();
      ln_apply_s<4, 8, 8>(lane, zB, mu, inv, g4, b4);
      wsync();
      int cb = (u < 8) ? 56 : 60;
      size_t obase = (size_t)bi * 4096 + (size_t)cb * 64 + (size_t)(u & 7) * 8;
      for (int id = lane; id < 32; id += 64) {
        int co = id >> 3, ll = id & 7;
        out[obase + (size_t)co * 64 + ll] = zB[co * 8 + ll];
      }
      wsync();
    }
  }
}

extern "C" void kernel_launch(void* const* d_in, const int* in_sizes, int n_in,
                              void* d_out, int out_size, void* d_ws, size_t ws_size,
                              hipStream_t stream) {
  const float* x   = (const float*)d_in[0];
  const float* w1  = (const float*)d_in[1];
  const float* w2  = (const float*)d_in[2];
  const float* w3  = (const float*)d_in[3];
  const float* w4  = (const float*)d_in[4];
  const float* f1  = (const float*)d_in[5];
  const float* f2  = (const float*)d_in[6];
  const float* f3  = (const float*)d_in[7];
  const float* f4  = (const float*)d_in[8];
  const float* l1g = (const float*)d_in[9];
  const float* l1b = (const float*)d_in[10];
  const float* l2g = (const float*)d_in[11];
  const float* l2b = (const float*)d_in[12];
  const float* l3g = (const float*)d_in[13];
  const float* l3b = (const float*)d_in[14];
  const float* l4g = (const float*)d_in[15];
  const float* l4b = (const float*)d_in[16];
  float* out = (float*)d_out;
  float* samp = (float*)d_ws;   // 151 MB staging

  k_prep<<<4096, 256, 0, stream>>>(x, samp);
  k_conv<<<4096, 256, 0, stream>>>(samp, w1, w2, w3, w4, f1, f2, f3, f4,
                                   l1g, l1b, l2g, l2b, l3g, l3b, l4g, l4b, out);
}